// Round 8
// baseline (33.720 us; speedup 1.0000x reference)
//
#include <hip/hip_runtime.h>
#include <float.h>
#include <math.h>

#define BB 8
#define PP 4096
#define NBLK 512           // 2 dirs x 8 clouds x 32 qgroups -> 2 blocks/CU
#define THREADS 512        // 8 waves
#define QB 128             // queries per block (4 itiles)

typedef __attribute__((ext_vector_type(8))) short bf16x8;
typedef __attribute__((ext_vector_type(16))) float f32x16;

__device__ __forceinline__ unsigned int f2bf(float f) {
    unsigned int u = __float_as_uint(f);
    return (u + 0x7FFFu + ((u >> 16) & 1u)) >> 16;   // RNE bf16
}
__device__ __forceinline__ float bf2f(unsigned int h) {
    return __uint_as_float(h << 16);
}
__device__ __forceinline__ float min3f(float a, float b, float c) {
    return fminf(fminf(a, b), c);                    // fuses to v_min3_f32
}

// One block = (dir, cloud, qgroup of 128 queries) vs all 4096 neighbors.
// MFMA computes t_ji = h_j - a_i.c_j (split-precision bf16 packed into K);
// d^2 = |a|^2 + 2*min_j t.  D[j,i]: col=lane&31 (query), rows over regs/lane-half.
// Wave w = jh in [0,8): owns 8 jtiles per half, all 4 itiles (4 MFMA per A-frag read).
__global__ __launch_bounds__(THREADS, 4) void chamfer_mfma(
    const float* __restrict__ y1, const float* __restrict__ y2,
    float* __restrict__ partials, int* __restrict__ counter,
    float* __restrict__ out)
{
    __shared__ uint4 fbuf[64 * 64];   // 64 KB: A-frags for 64 jtiles (half cloud)

    const int bid   = blockIdx.x;
    const int qg    = bid & 31;
    const int cloud = (bid >> 5) & 7;
    const int dir   = bid >> 8;

    const float* src = (dir == 0) ? y1 : y2;
    const float* tgt = (dir == 0) ? y2 : y1;
    const float* __restrict__ tgt_base = tgt + (size_t)cloud * PP * 3;
    const float* __restrict__ src_base = src + ((size_t)cloud * PP + (size_t)qg * QB) * 3;

    const int tid  = threadIdx.x;
    const int lane = tid & 63;
    const int jh   = tid >> 6;   // wave id = jtile-range owner

    // ---- B-frags (queries) for the 4 itiles, built once in registers ----
    // lane<32 (k0..7):  [nahix,nahiy,nahiz, nalox,naloy,naloz, nahix,nahiy]
    // lane>=32 (k8..15):[nahiz, 1.0, 1.0, 0,0,0,0,0]
    bf16x8 bfrag[4];
    #pragma unroll
    for (int t = 0; t < 4; ++t) {
        const int ql = t * 32 + (lane & 31);
        const float ax = src_base[ql * 3 + 0];
        const float ay = src_base[ql * 3 + 1];
        const float az = src_base[ql * 3 + 2];
        const unsigned int hx = f2bf(-ax), hy = f2bf(-ay), hz = f2bf(-az);
        const unsigned int lx = f2bf(-ax - bf2f(hx));
        const unsigned int ly = f2bf(-ay - bf2f(hy));
        const unsigned int lz = f2bf(-az - bf2f(hz));
        uint4 bb;
        if (lane < 32) {
            bb.x = hx | (hy << 16);
            bb.y = hz | (lx << 16);
            bb.z = ly | (lz << 16);
            bb.w = hx | (hy << 16);
        } else {
            bb.x = hz | (0x3F80u << 16);   // k8 = nahiz, k9 = 1.0
            bb.y = 0x3F80u;                // k10 = 1.0, k11 = 0
            bb.z = 0u;
            bb.w = 0u;
        }
        bfrag[t] = *reinterpret_cast<bf16x8*>(&bb);
    }

    float m[4][4];
    #pragma unroll
    for (int t = 0; t < 4; ++t)
        #pragma unroll
        for (int r = 0; r < 4; ++r)
            m[t][r] = FLT_MAX;

    f32x16 zc;
    #pragma unroll
    for (int r = 0; r < 16; ++r) zc[r] = 0.0f;

    for (int half = 0; half < 2; ++half) {
        // ---- Build A-frags for neighbors half*2048 .. +2047 (4 per thread) ----
        // A lane<32 (k0..7):  [chix,chiy,chiz, chix,chiy,chiz, clox,cloy]
        // A lane>=32 (k8..15):[cloz, h_hi, h_lo, 0,0,0,0,0]
        #pragma unroll
        for (int rep = 0; rep < 4; ++rep) {
            const int nl = rep * THREADS + tid;          // 0..2047 within half
            const int n  = half * 2048 + nl;
            const float cx = tgt_base[n * 3 + 0];
            const float cy = tgt_base[n * 3 + 1];
            const float cz = tgt_base[n * 3 + 2];
            const unsigned int chx = f2bf(cx), chy = f2bf(cy), chz = f2bf(cz);
            const unsigned int clx = f2bf(cx - bf2f(chx));
            const unsigned int cly = f2bf(cy - bf2f(chy));
            const unsigned int clz = f2bf(cz - bf2f(chz));
            const float hh = 0.5f * (cx * cx + cy * cy + cz * cz);
            const unsigned int hhi = f2bf(hh);
            const unsigned int hlo = f2bf(hh - bf2f(hhi));
            const int tile = nl >> 5, r = nl & 31;
            uint4 lof, hif;
            lof.x = chx | (chy << 16);
            lof.y = chz | (chx << 16);
            lof.z = chy | (chz << 16);
            lof.w = clx | (cly << 16);
            hif.x = clz | (hhi << 16);
            hif.y = hlo;
            hif.z = 0u;
            hif.w = 0u;
            fbuf[tile * 64 + r]      = lof;
            fbuf[tile * 64 + 32 + r] = hif;
        }
        __syncthreads();

        // ---- Main loop: 8 jtiles, 1 A-frag read + 4 MFMA each ----
        const int jt0 = jh * 8;
        bf16x8 af = *reinterpret_cast<const bf16x8*>(&fbuf[jt0 * 64 + lane]);
        for (int jt = 0; jt < 8; ++jt) {
            bf16x8 afn = af;
            if (jt < 7)
                afn = *reinterpret_cast<const bf16x8*>(&fbuf[(jt0 + jt + 1) * 64 + lane]);
            #pragma unroll
            for (int t = 0; t < 4; ++t) {
                f32x16 acc = __builtin_amdgcn_mfma_f32_32x32x16_bf16(af, bfrag[t], zc, 0, 0, 0);
                m[t][0] = min3f(m[t][0], acc[0], acc[4]);
                m[t][1] = min3f(m[t][1], acc[1], acc[5]);
                m[t][2] = min3f(m[t][2], acc[2], acc[6]);
                m[t][3] = min3f(m[t][3], acc[3], acc[7]);
                m[t][0] = min3f(m[t][0], acc[8], acc[12]);
                m[t][1] = min3f(m[t][1], acc[9], acc[13]);
                m[t][2] = min3f(m[t][2], acc[10], acc[14]);
                m[t][3] = min3f(m[t][3], acc[11], acc[15]);
            }
            af = afn;
        }
        __syncthreads();   // frags fully consumed before rebuild / reuse
    }

    // ---- Epilogue: fold mins, merge lane-halves, cross-wave min, distance, sum ----
    float* pmin = reinterpret_cast<float*>(fbuf);   // [8][QB], aliases fbuf
    float* ssum = pmin + 8 * QB;                    // 2 floats
    #pragma unroll
    for (int t = 0; t < 4; ++t) {
        float mm = fminf(fminf(m[t][0], m[t][1]), fminf(m[t][2], m[t][3]));
        mm = fminf(mm, __shfl_xor(mm, 32));
        if (lane < 32)
            pmin[jh * QB + t * 32 + (lane & 31)] = mm;
    }
    __syncthreads();
    if (tid < QB) {
        float v = pmin[tid];
        #pragma unroll
        for (int g = 1; g < 8; ++g)
            v = fminf(v, pmin[g * QB + tid]);
        const float ax = src_base[tid * 3 + 0];
        const float ay = src_base[tid * 3 + 1];
        const float az = src_base[tid * 3 + 2];
        const float aa = ax * ax + ay * ay + az * az;
        float d = sqrtf(fmaxf(0.0f, fmaf(2.0f, v, aa)));
        #pragma unroll
        for (int off = 32; off > 0; off >>= 1)
            d += __shfl_down(d, off);
        if ((tid & 63) == 0)
            ssum[tid >> 6] = d;
    }
    __syncthreads();

    // ---- Fused cross-block finalize (deterministic fixed-order sum) ----
    __shared__ int lastflag;
    if (tid == 0) {
        partials[bid] = ssum[0] + ssum[1];
        __threadfence();                              // publish partial (device scope)
        const int ticket = atomicAdd(counter, 1);
        lastflag = (ticket == NBLK - 1) ? 1 : 0;
    }
    __syncthreads();
    if (lastflag && tid < 64) {
        __threadfence();
        float s = 0.0f;
        #pragma unroll
        for (int k = 0; k < NBLK / 64; ++k)           // fixed order: k-major, lane-minor
            s += __hip_atomic_load(&partials[k * 64 + tid],
                                   __ATOMIC_RELAXED, __HIP_MEMORY_SCOPE_AGENT);
        #pragma unroll
        for (int off = 32; off > 0; off >>= 1)
            s += __shfl_down(s, off);
        if (tid == 0)
            out[0] = s * (1.0f / (float)(BB * PP));
    }
}

extern "C" void kernel_launch(void* const* d_in, const int* in_sizes, int n_in,
                              void* d_out, int out_size, void* d_ws, size_t ws_size,
                              hipStream_t stream) {
    const float* y1 = (const float*)d_in[0];
    const float* y2 = (const float*)d_in[1];
    float* partials = (float*)d_ws;                       // NBLK floats
    int*   counter  = (int*)((char*)d_ws + NBLK * 4);     // 1 int, zeroed each call
    float* out      = (float*)d_out;

    hipMemsetAsync(counter, 0, sizeof(int), stream);
    chamfer_mfma<<<NBLK, THREADS, 0, stream>>>(y1, y2, partials, counter, out);
}

// Round 9
// 17.428 us; speedup vs baseline: 1.9348x; 1.9348x over previous
//
#include <hip/hip_runtime.h>
#include <float.h>
#include <math.h>

#define BB 8
#define PP 4096

typedef __attribute__((ext_vector_type(8))) short bf16x8;
typedef __attribute__((ext_vector_type(16))) float f32x16;

__device__ __forceinline__ unsigned int f2bf(float f) {
    unsigned int u = __float_as_uint(f);
    return (u + 0x7FFFu + ((u >> 16) & 1u)) >> 16;   // RNE bf16
}
__device__ __forceinline__ float bf2f(unsigned int h) {
    return __uint_as_float(h << 16);
}
__device__ __forceinline__ float min3f(float a, float b, float c) {
    return fminf(fminf(a, b), c);                    // fuses to v_min3_f32
}

// One block = (dir, cloud, qgroup of 256 queries) vs all 4096 neighbors.
// MFMA computes t_ji = h_j - a_i.c_j (split-precision bf16 packed into K);
// d^2 = |a|^2 + 2*min_j t.  D[j,i]: col=lane&31 (query), rows over regs/lane-half.
// Wave w owns itile (w&7), jtile-half (w>>3). 2-deep pipelined min-fold:
// fold(acc_prev) overlaps mfma(acc_cur) latency.
__global__ __launch_bounds__(1024) void chamfer_mfma(
    const float* __restrict__ y1, const float* __restrict__ y2,
    float* __restrict__ partial)
{
    __shared__ uint4 fbuf[64 * 64];   // 64 KB: A-frags for 64 jtiles (half cloud)

    const int bid   = blockIdx.x;
    const int qg    = bid & 15;
    const int cloud = (bid >> 4) & 7;
    const int dir   = bid >> 7;

    const float* src = (dir == 0) ? y1 : y2;
    const float* tgt = (dir == 0) ? y2 : y1;
    const float* __restrict__ tgt_base = tgt + (size_t)cloud * PP * 3;
    const float* __restrict__ src_base = src + ((size_t)cloud * PP + (size_t)qg * 256) * 3;

    const int tid  = threadIdx.x;
    const int lane = tid & 63;
    const int w    = tid >> 6;
    const int ig   = w & 7;     // itile (32 queries) this wave owns
    const int jh   = w >> 3;    // which 32-jtile half-range this wave owns

    // ---- B-frag (queries), built once in registers ----
    // lane<32 (k0..7):  [nahix,nahiy,nahiz, nalox,naloy,naloz, nahix,nahiy]
    // lane>=32 (k8..15):[nahiz, 1.0, 1.0, 0,0,0,0,0]
    bf16x8 bfrag;
    {
        const int ql = ig * 32 + (lane & 31);
        const float ax = src_base[ql * 3 + 0];
        const float ay = src_base[ql * 3 + 1];
        const float az = src_base[ql * 3 + 2];
        const unsigned int hx = f2bf(-ax), hy = f2bf(-ay), hz = f2bf(-az);
        const unsigned int lx = f2bf(-ax - bf2f(hx));
        const unsigned int ly = f2bf(-ay - bf2f(hy));
        const unsigned int lz = f2bf(-az - bf2f(hz));
        uint4 bb;
        if (lane < 32) {
            bb.x = hx | (hy << 16);
            bb.y = hz | (lx << 16);
            bb.z = ly | (lz << 16);
            bb.w = hx | (hy << 16);
        } else {
            bb.x = hz | (0x3F80u << 16);   // k8 = nahiz, k9 = 1.0
            bb.y = 0x3F80u;                // k10 = 1.0, k11 = 0
            bb.z = 0u;
            bb.w = 0u;
        }
        bfrag = *reinterpret_cast<bf16x8*>(&bb);
    }

    float m0 = FLT_MAX, m1 = FLT_MAX, m2 = FLT_MAX, m3 = FLT_MAX;

    f32x16 zc;
    #pragma unroll
    for (int r = 0; r < 16; ++r) zc[r] = 0.0f;

#define FOLD(acc)                              \
    do {                                       \
        m0 = min3f(m0, (acc)[0], (acc)[4]);    \
        m1 = min3f(m1, (acc)[1], (acc)[5]);    \
        m2 = min3f(m2, (acc)[2], (acc)[6]);    \
        m3 = min3f(m3, (acc)[3], (acc)[7]);    \
        m0 = min3f(m0, (acc)[8], (acc)[12]);   \
        m1 = min3f(m1, (acc)[9], (acc)[13]);   \
        m2 = min3f(m2, (acc)[10], (acc)[14]);  \
        m3 = min3f(m3, (acc)[11], (acc)[15]);  \
    } while (0)

    for (int half = 0; half < 2; ++half) {
        // ---- Build A-frags for neighbors half*2048 .. +2047 ----
        // A lane<32 (k0..7):  [chix,chiy,chiz, chix,chiy,chiz, clox,cloy]
        // A lane>=32 (k8..15):[cloz, h_hi, h_lo, 0,0,0,0,0]
        #pragma unroll
        for (int rep = 0; rep < 2; ++rep) {
            const int nl = rep * 1024 + tid;            // 0..2047 within half
            const int n  = half * 2048 + nl;
            const float cx = tgt_base[n * 3 + 0];
            const float cy = tgt_base[n * 3 + 1];
            const float cz = tgt_base[n * 3 + 2];
            const unsigned int chx = f2bf(cx), chy = f2bf(cy), chz = f2bf(cz);
            const unsigned int clx = f2bf(cx - bf2f(chx));
            const unsigned int cly = f2bf(cy - bf2f(chy));
            const unsigned int clz = f2bf(cz - bf2f(chz));
            const float hh = 0.5f * (cx * cx + cy * cy + cz * cz);
            const unsigned int hhi = f2bf(hh);
            const unsigned int hlo = f2bf(hh - bf2f(hhi));
            const int tile = nl >> 5, r = nl & 31;
            uint4 lof, hif;
            lof.x = chx | (chy << 16);
            lof.y = chz | (chx << 16);
            lof.z = chy | (chz << 16);
            lof.w = clx | (cly << 16);
            hif.x = clz | (hhi << 16);
            hif.y = hlo;
            hif.z = 0u;
            hif.w = 0u;
            fbuf[tile * 64 + r]      = lof;
            fbuf[tile * 64 + 32 + r] = hif;
        }
        __syncthreads();

        // ---- Main loop: 32 jtiles, 2-deep pipelined fold ----
        const uint4* __restrict__ fb = &fbuf[(size_t)(jh * 32) * 64 + lane];
        bf16x8 afA = *reinterpret_cast<const bf16x8*>(fb);
        f32x16 accA = __builtin_amdgcn_mfma_f32_32x32x16_bf16(afA, bfrag, zc, 0, 0, 0);
        bf16x8 afB;
        f32x16 accB;
        for (int jt = 1; jt < 31; jt += 2) {
            afB  = *reinterpret_cast<const bf16x8*>(fb + (size_t)jt * 64);
            accB = __builtin_amdgcn_mfma_f32_32x32x16_bf16(afB, bfrag, zc, 0, 0, 0);
            FOLD(accA);                    // overlaps accB's latency
            afA  = *reinterpret_cast<const bf16x8*>(fb + (size_t)(jt + 1) * 64);
            accA = __builtin_amdgcn_mfma_f32_32x32x16_bf16(afA, bfrag, zc, 0, 0, 0);
            FOLD(accB);                    // overlaps accA's latency
        }
        afB  = *reinterpret_cast<const bf16x8*>(fb + (size_t)31 * 64);
        accB = __builtin_amdgcn_mfma_f32_32x32x16_bf16(afB, bfrag, zc, 0, 0, 0);
        FOLD(accA);
        FOLD(accB);
        __syncthreads();   // frags fully consumed before rebuild / reuse
    }
#undef FOLD

    // ---- Epilogue: fold 4 mins, merge lane-halves, cross-jh min, distance, sum ----
    float* pmin = reinterpret_cast<float*>(fbuf);   // [2][256], aliases fbuf
    float* ssum = pmin + 512;                       // 4 floats
    {
        float mm = fminf(fminf(m0, m1), fminf(m2, m3));
        mm = fminf(mm, __shfl_xor(mm, 32));
        if (lane < 32)
            pmin[jh * 256 + ig * 32 + (lane & 31)] = mm;
    }
    __syncthreads();
    if (tid < 256) {
        float v = fminf(pmin[tid], pmin[256 + tid]);
        const float ax = src_base[tid * 3 + 0];
        const float ay = src_base[tid * 3 + 1];
        const float az = src_base[tid * 3 + 2];
        const float aa = ax * ax + ay * ay + az * az;
        float d = sqrtf(fmaxf(0.0f, fmaf(2.0f, v, aa)));
        #pragma unroll
        for (int off = 32; off > 0; off >>= 1)
            d += __shfl_down(d, off);
        if ((tid & 63) == 0)
            ssum[tid >> 6] = d;
    }
    __syncthreads();
    if (tid == 0)
        partial[bid] = ssum[0] + ssum[1] + ssum[2] + ssum[3];
}

// Sum 256 block partials, normalize by B*P (gives d1 + d2).
__global__ __launch_bounds__(256) void chamfer_final(
    const float* __restrict__ partial, float* __restrict__ out)
{
    __shared__ float ssum[4];
    const int tid = threadIdx.x;
    float v = partial[tid];
    #pragma unroll
    for (int off = 32; off > 0; off >>= 1)
        v += __shfl_down(v, off);
    if ((tid & 63) == 0)
        ssum[tid >> 6] = v;
    __syncthreads();
    if (tid == 0)
        out[0] = (ssum[0] + ssum[1] + ssum[2] + ssum[3]) * (1.0f / (float)(BB * PP));
}

extern "C" void kernel_launch(void* const* d_in, const int* in_sizes, int n_in,
                              void* d_out, int out_size, void* d_ws, size_t ws_size,
                              hipStream_t stream) {
    const float* y1 = (const float*)d_in[0];
    const float* y2 = (const float*)d_in[1];
    float* partial = (float*)d_ws;    // 256 floats of scratch
    float* out     = (float*)d_out;

    chamfer_mfma<<<256, 1024, 0, stream>>>(y1, y2, partial);
    chamfer_final<<<1, 256, 0, stream>>>(partial, out);
}